// Round 1
// 457.907 us; speedup vs baseline: 1.0695x; 1.0695x over previous
//
#include <hip/hip_runtime.h>
#include <math.h>

// Fused Conv2d(64->128,3x3,valid) + bias + min(oc) + tanh(tanh()) via
// bf16 MFMA implicit GEMM (mfma_f32_32x32x16_bf16).
//
// Round 6: de-serialize the x staging phase.
//  - All ~72 stage loads per thread are issued BEFORE any conversion
//    (one HBM latency round instead of nine). launch_bounds(256,4)
//    caps VGPR at 128 so 4 blocks/CU (LDS 135KB) stay resident.
//  - f32->bf16 via v_cvt_pk_bf16_f32 (2 elems/instr, RNE — bit-identical
//    to the previous manual rounding), ~6x less stage VALU.
//  - B-pipeline register loads issued before stage loads (L2 latency
//    hides under staging).
// K-loop / epilogue unchanged from round 5:
//  - B: 3-stage register pipeline, prefetch distance 2 ksteps.
//  - A: 1-kstep-ahead ds_read_b128 prefetch.
// Block: 256 thr = 4 waves; tile 2 rows x 64 cols x 128 oc.
// LDS: xt[(row4*4+icc)*2+hi][col66][j8] bf16 = 33792 B.
// Epilogue: LDS transpose (sm[128][65] overlay) + row-min + shfl_xor.

typedef __attribute__((ext_vector_type(8))) short bf16x8;
typedef __attribute__((ext_vector_type(16))) float f32x16;

static __device__ __forceinline__ short f2bf(float f) {
    unsigned u = __float_as_uint(f);
    u += 0x7fffu + ((u >> 16) & 1u);
    return (short)(u >> 16);
}

// v_cvt_pk_bf16_f32: D[15:0]=bf16(a), D[31:16]=bf16(b), round-nearest-even.
static __device__ __forceinline__ unsigned cvt_pk_bf16(float a, float b) {
    unsigned r;
    asm("v_cvt_pk_bf16_f32 %0, %1, %2" : "=v"(r) : "v"(a), "v"(b));
    return r;
}

// d_ws layout: bf16 bits, idx = ((kstep*2 + hi)*128 + oc)*8 + j
// kstep = tap*4 + icc, tap = kh*3 + kw, ic = icc*16 + hi*8 + j. 73728 elems.
__global__ void wtrans(const float* __restrict__ wg, short* __restrict__ wsB) {
    int o4 = blockIdx.x * 256 + threadIdx.x;   // 0..18431 (x4 elements)
    if (o4 >= 18432) return;
    float4 v = ((const float4*)wg)[o4];        // coalesced read
    float f[4] = {v.x, v.y, v.z, v.w};
    int base = o4 * 4;
    #pragma unroll
    for (int q = 0; q < 4; ++q) {
        int e  = base + q;                     // ((oc*64+ic)*3+kh)*3+kw
        int kw = e % 3, r1 = e / 3;
        int kh = r1 % 3, r2 = r1 / 3;
        int ic = r2 & 63, oc = r2 >> 6;
        int tap = kh * 3 + kw;
        int icc = ic >> 4, hi = (ic >> 3) & 1, j = ic & 7;
        int kstep = tap * 4 + icc;
        wsB[((kstep * 2 + hi) * 128 + oc) * 8 + j] = f2bf(f[q]);
    }
}

__global__ __launch_bounds__(256, 4)
void conv_min_tanh_mfma(const float* __restrict__ xg,
                        const short* __restrict__ wsB,
                        const float* __restrict__ bg,
                        float* __restrict__ out) {
    __shared__ __align__(16) short xt[16896];  // [32 g][66 col][8 j] = 33792 B

    const int tid  = threadIdx.x;
    const int lane = tid & 63, l31 = lane & 31, hi = lane >> 5;
    const int w    = tid >> 6;
    const int r    = w & 1;        // output row within pair
    const int nh   = w >> 1;       // oc half
    const int ow0  = blockIdx.x * 64;
    const int oh0  = blockIdx.y * 2;
    const int b    = blockIdx.z;

    // ---- B pipeline: issue register loads first (wsB is L2-resident;
    // latency hides under the x staging below). Consumed after barrier.
    const bf16x8* bbase = (const bf16x8*)(wsB + ((size_t)hi * 128 + nh * 64 + l31) * 8);
    bf16x8 bc0 = bbase[0],   bc1 = bbase[32];         // k=0
    bf16x8 bd0 = bbase[256], bd1 = bbase[256 + 32];   // k=1

    // ---- stage x: rows oh0..+3, cols ow0..+65, 64 ic -> 2112 bf16x8 vectors
    // Phase A: issue ALL global loads (up to 72/thread in flight).
    float f[9][8];
    #pragma unroll
    for (int t = 0; t < 9; ++t) {
        int idx = t * 256 + tid;
        if (idx < 2112) {                      // always true for t<8
            int g   = idx / 66;                // (row*4+icc)*2+hi
            int col = idx - g * 66;
            int row = g >> 3;
            int icb = ((g >> 1) & 3) * 16 + (g & 1) * 8;
            int iw  = ow0 + col;
            const float* src = xg + (((size_t)(b * 64 + icb) * 256) + (oh0 + row)) * 256 + iw;
            bool valid = iw < 256;
            #pragma unroll
            for (int j = 0; j < 8; ++j) f[t][j] = valid ? src[j * 65536] : 0.f;
        }
    }
    // Phase B: convert (v_cvt_pk_bf16_f32) + LDS write.
    #pragma unroll
    for (int t = 0; t < 9; ++t) {
        int idx = t * 256 + tid;
        if (idx < 2112) {
            int g   = idx / 66;
            int col = idx - g * 66;
            bf16x8 v;
            unsigned* vp = (unsigned*)&v;
            #pragma unroll
            for (int p = 0; p < 4; ++p)
                vp[p] = cvt_pk_bf16(f[t][2 * p], f[t][2 * p + 1]);
            *(bf16x8*)(xt + g * 528 + col * 8) = v;
        }
    }

    bf16x8 be0 = bd0, be1 = bd1;

    __syncthreads();   // the only K-side barrier

    f32x16 acc00 = {}, acc01 = {}, acc10 = {}, acc11 = {};

    // A fragments for kstep 0 (tap 0 -> kh=kw=0, icc=0)
    const bf16x8* ap0 = (const bf16x8*)(xt + ((r * 4 + 0) * 2 + hi) * 528 + l31 * 8);
    bf16x8 a0 = ap0[0], a1 = ap0[32];

    #pragma unroll
    for (int k = 0; k < 36; ++k) {
        // issue B prefetch for k+2 (2 loads; 6 in flight max)
        if (k < 34) {
            be0 = bbase[(k + 2) * 256];
            be1 = bbase[(k + 2) * 256 + 32];
        }
        // issue A prefetch for k+1 (2 ds_read_b128)
        bf16x8 an0 = a0, an1 = a1;
        if (k < 35) {
            const int kn = k + 1, tapn = kn >> 2, iccn = kn & 3;
            const int khn = tapn / 3, kwn = tapn - khn * 3;
            const bf16x8* apn = (const bf16x8*)(xt +
                (((r + khn) * 4 + iccn) * 2 + hi) * 528 + (l31 + kwn) * 8);
            an0 = apn[0];
            an1 = apn[32];
        }
        acc00 = __builtin_amdgcn_mfma_f32_32x32x16_bf16(a0, bc0, acc00, 0, 0, 0);
        acc01 = __builtin_amdgcn_mfma_f32_32x32x16_bf16(a0, bc1, acc01, 0, 0, 0);
        acc10 = __builtin_amdgcn_mfma_f32_32x32x16_bf16(a1, bc0, acc10, 0, 0, 0);
        acc11 = __builtin_amdgcn_mfma_f32_32x32x16_bf16(a1, bc1, acc11, 0, 0, 0);
        // rotate pipelines
        a0 = an0; a1 = an1;
        bc0 = bd0; bc1 = bd1;
        bd0 = be0; bd1 = be1;
    }

    // ---- epilogue: bias + partial min (2 oc/lane) -> LDS transpose -> min
    __syncthreads();                  // all xt reads done; overlay as sm
    float* sm = (float*)xt;           // [128 px][65] floats = 33280 B
    const float bv0 = bg[nh * 64 + l31];
    const float bv1 = bg[nh * 64 + 32 + l31];
    #pragma unroll
    for (int reg = 0; reg < 16; ++reg) {
        // D layout (32x32): n = lane&31, m = (reg&3) + 8*(reg>>2) + 4*hi
        const int m = (reg & 3) + 8 * (reg >> 2) + 4 * hi;
        float p0 = fminf(acc00[reg] + bv0, acc01[reg] + bv1);
        float p1 = fminf(acc10[reg] + bv0, acc11[reg] + bv1);
        sm[(r * 64 + m) * 65 + nh * 32 + l31]      = p0;
        sm[(r * 64 + 32 + m) * 65 + nh * 32 + l31] = p1;
    }
    __syncthreads();
    {
        const int px = tid >> 1, half = tid & 1;   // px 0..127
        const float* rowp = sm + px * 65 + half * 32;
        float v = rowp[0];
        #pragma unroll
        for (int j = 1; j < 32; ++j) v = fminf(v, rowp[j]);
        v = fminf(v, __shfl_xor(v, 1, 64));
        if (half == 0) {
            v = tanhf(tanhf(v));
            const int ow = ow0 + (px & 63);
            const int oh = oh0 + (px >> 6);
            if (ow < 254)
                out[((size_t)b * 254 + oh) * 254 + ow] = v;
        }
    }
}

extern "C" void kernel_launch(void* const* d_in, const int* in_sizes, int n_in,
                              void* d_out, int out_size, void* d_ws, size_t ws_size,
                              hipStream_t stream) {
    const float* x  = (const float*)d_in[0];   // (16,64,256,256)
    const float* wg = (const float*)d_in[1];   // (128,64,3,3)
    const float* bs = (const float*)d_in[2];   // (128,)
    float* out = (float*)d_out;                // (16,1,254,254)
    short* wsB = (short*)d_ws;                 // needs 147456 B

    wtrans<<<72, 256, 0, stream>>>(wg, wsB);
    dim3 grid(4, 127, 16);   // ow tiles, oh pairs, batch
    conv_min_tanh_mfma<<<grid, 256, 0, stream>>>(x, wsB, bs, out);
}